// Round 3
// baseline (452.314 us; speedup 1.0000x reference)
//
#include <hip/hip_runtime.h>
#include <hip/hip_cooperative_groups.h>

namespace cg = cooperative_groups;

#define EPS 1e-5f

// Problem dims (fixed by setup_inputs)
constexpr int T  = 512;
constexpr int B  = 64;
constexpr int HU = 1024;
constexpr int S  = 1024;
constexpr int C  = B * HU;       // 65536 output columns

// ws layout (floats)
constexpr size_t OFF_SIW0 = 0;      // [64][10]
constexpr size_t OFF_BM   = 640;    // [512] per-block score max
constexpr size_t OFF_PZ   = 1152;   // [512] per-block sum exp(s - bm)
constexpr size_t OFF_A    = 1664;   // [512] softmax weights used by wsum

struct Params {
    const float *si, *h, *W0, *b0, *g0, *be0, *m0, *v0;
    const float *W1, *b1, *g1, *be1, *m1, *v1, *W2, *b2;
    float *ws;
    float *out;
};

// One cooperative kernel: scores MLP -> hierarchical global softmax -> weighted sum.
// 512 blocks x 256 threads, 2 blocks/CU co-resident, 3 grid syncs.
__global__ __launch_bounds__(256, 2) void k_fused(Params P) {
    cg::grid_group grid = cg::this_grid();
    const int bid = blockIdx.x;      // 0..511 (= t for the scores phase)
    const int tid = threadIdx.x;     // 0..255
    const int wv  = tid >> 6;        // 0..3
    const int ln  = tid & 63;        // 0..63 (= b for the scores phase)

    float* siW0 = P.ws + OFF_SIW0;
    float* bmv  = P.ws + OFF_BM;
    float* pzv  = P.ws + OFF_PZ;
    float* av   = P.ws + OFF_A;

    __shared__ float s_part[4][64][10];   // per-wave k-slice partials
    __shared__ float s_red[64];           // small reductions

    // ---------------- Phase A: scores main loop (lane ln owns row p) -------
    // Wave wv covers k in [256wv, 256wv+256); W0 index wave-uniform -> s_load;
    // per 128B line the lane issues 8 back-to-back float4 loads.
    {
        const float* hrow = P.h + (size_t)(bid * 64 + ln) * HU;
        const int k0 = __builtin_amdgcn_readfirstlane(wv * 256);
        float acc[10];
#pragma unroll
        for (int j = 0; j < 10; ++j) acc[j] = 0.f;
#pragma unroll 2
        for (int w8 = 0; w8 < 8; ++w8) {
            const int kb = k0 + 32 * w8;
            float4 hv[8];
#pragma unroll
            for (int q = 0; q < 8; ++q)
                hv[q] = *(const float4*)(hrow + kb + 4 * q);
            const float* wp = P.W0 + (size_t)(1024 + kb) * 10;
#pragma unroll
            for (int q = 0; q < 8; ++q) {
#pragma unroll
                for (int d = 0; d < 4; ++d) {
                    const float hx = (&hv[q].x)[d];
#pragma unroll
                    for (int j = 0; j < 10; ++j)
                        acc[j] = fmaf(hx, wp[(q * 4 + d) * 10 + j], acc[j]);
                }
            }
        }
#pragma unroll
        for (int j = 0; j < 10; ++j) s_part[wv][ln][j] = acc[j];
    }

    // Side jobs while other blocks crunch: blocks 0..63 compute siW0[b][:],
    // blocks 64..127 zero d_out (it is poisoned 0xAA; phase D atomicAdds).
    if (bid < 64) {
        const float4 sv = ((const float4*)(P.si + (size_t)bid * S))[tid];
        const float* wp = P.W0 + (size_t)(4 * tid) * 10;
        float sa[10];
#pragma unroll
        for (int j = 0; j < 10; ++j) sa[j] = 0.f;
#pragma unroll
        for (int d = 0; d < 4; ++d) {
            const float hx = (&sv.x)[d];
#pragma unroll
            for (int j = 0; j < 10; ++j) sa[j] = fmaf(hx, wp[d * 10 + j], sa[j]);
        }
#pragma unroll
        for (int j = 0; j < 10; ++j) {
#pragma unroll
            for (int off = 32; off > 0; off >>= 1)
                sa[j] += __shfl_down(sa[j], off, 64);
        }
        __syncthreads();                     // block-uniform branch: safe
        if (ln == 0) {
#pragma unroll
            for (int j = 0; j < 10; ++j) s_red[wv * 16 + j] = sa[j];
        }
        __syncthreads();
        if (tid < 10)
            siW0[(size_t)bid * 10 + tid] = s_red[0 * 16 + tid] + s_red[1 * 16 + tid] +
                                           s_red[2 * 16 + tid] + s_red[3 * 16 + tid];
    } else if (bid < 128) {
        const float4 z4 = {0.f, 0.f, 0.f, 0.f};
        *(float4*)(P.out + (size_t)(bid - 64) * 1024 + tid * 4) = z4;
    }

    grid.sync();   // S1: siW0 + out-zero + LDS partials ready

    // ---------------- Phase B: MLP epilogue -> sc, block max, block partZ ---
    float sc = 0.f;                          // kept live into phase C (blocks<8)
    if (wv == 0) {
        float y[10];
#pragma unroll
        for (int j = 0; j < 10; ++j) {
            float u = s_part[0][ln][j] + s_part[1][ln][j] + s_part[2][ln][j] +
                      s_part[3][ln][j] + siW0[(size_t)ln * 10 + j] + P.b0[j];
            u = (u - P.m0[j]) * (1.0f / sqrtf(P.v0[j] + EPS)) * P.g0[j] + P.be0[j];
            y[j] = fmaxf(u, 0.f);
        }
        float z[5];
#pragma unroll
        for (int i = 0; i < 5; ++i) {
            float u = P.b1[i];
#pragma unroll
            for (int j = 0; j < 10; ++j) u = fmaf(y[j], P.W1[j * 5 + i], u);
            u = (u - P.m1[i]) * (1.0f / sqrtf(P.v1[i] + EPS)) * P.g1[i] + P.be1[i];
            z[i] = fmaxf(u, 0.f);
        }
        sc = P.b2[0];
#pragma unroll
        for (int i = 0; i < 5; ++i) sc = fmaf(z[i], P.W2[i], sc);

        float bm = sc;                       // butterfly max -> all lanes
#pragma unroll
        for (int off = 32; off > 0; off >>= 1)
            bm = fmaxf(bm, __shfl_xor(bm, off, 64));
        float e = __expf(sc - bm);
#pragma unroll
        for (int off = 32; off > 0; off >>= 1)
            e += __shfl_xor(e, off, 64);
        if (ln == 0) { bmv[bid] = bm; pzv[bid] = e; }
    }

    grid.sync();   // S2: all 512 (bm, partZ) pairs visible

    // ---------------- Phase C: blocks 0..7 finalize m, Z; write a[0:512] ----
    if (bid < 8) {
        float lm = fmaxf(bmv[tid], bmv[tid + 256]);
#pragma unroll
        for (int off = 32; off > 0; off >>= 1)
            lm = fmaxf(lm, __shfl_xor(lm, off, 64));
        if (ln == 0) s_red[wv] = lm;
        __syncthreads();
        const float m = fmaxf(fmaxf(s_red[0], s_red[1]), fmaxf(s_red[2], s_red[3]));
        __syncthreads();
        float lz = pzv[tid] * __expf(bmv[tid] - m) +
                   pzv[tid + 256] * __expf(bmv[tid + 256] - m);
#pragma unroll
        for (int off = 32; off > 0; off >>= 1)
            lz += __shfl_xor(lz, off, 64);
        if (ln == 0) s_red[wv] = lz;
        __syncthreads();
        const float Z = s_red[0] + s_red[1] + s_red[2] + s_red[3];
        // a[tau] for tau = bid*64 + ln; this block's own sc IS scores[tau]
        if (wv == 0) av[bid * 64 + ln] = __expf(sc - m) / Z;
    }

    grid.sync();   // S3: a[] visible everywhere

    // ---------------- Phase D: weighted sum, atomic accumulate -------------
    // block -> (ts = bid>>6 in [0,8), cb = bid&63); 64 taus, 1024 columns.
    {
        const int ts = bid >> 6;
        const int cb = bid & 63;
        const int c  = cb * 1024 + tid * 4;
        const float* hp = P.h + (size_t)ts * 64 * C + c;
        const float* ap = av + ts * 64;
        float4 s4 = {0.f, 0.f, 0.f, 0.f};
#pragma unroll 4
        for (int i = 0; i < 64; ++i) {
            const float a1 = ap[i];                        // uniform -> s_load
            const float4 hv = *(const float4*)(hp + (size_t)i * C);
            s4.x = fmaf(a1, hv.x, s4.x);
            s4.y = fmaf(a1, hv.y, s4.y);
            s4.z = fmaf(a1, hv.z, s4.z);
            s4.w = fmaf(a1, hv.w, s4.w);
        }
        atomicAdd(P.out + c + 0, s4.x);
        atomicAdd(P.out + c + 1, s4.y);
        atomicAdd(P.out + c + 2, s4.z);
        atomicAdd(P.out + c + 3, s4.w);
    }
}

// ---------------------------------------------------------------------------
extern "C" void kernel_launch(void* const* d_in, const int* in_sizes, int n_in,
                              void* d_out, int out_size, void* d_ws, size_t ws_size,
                              hipStream_t stream) {
    Params p;
    p.si  = (const float*)d_in[0];
    p.h   = (const float*)d_in[1];
    p.W0  = (const float*)d_in[2];
    p.b0  = (const float*)d_in[3];
    p.g0  = (const float*)d_in[4];
    p.be0 = (const float*)d_in[5];
    p.m0  = (const float*)d_in[6];
    p.v0  = (const float*)d_in[7];
    p.W1  = (const float*)d_in[8];
    p.b1  = (const float*)d_in[9];
    p.g1  = (const float*)d_in[10];
    p.be1 = (const float*)d_in[11];
    p.m1  = (const float*)d_in[12];
    p.v1  = (const float*)d_in[13];
    p.W2  = (const float*)d_in[14];
    p.b2  = (const float*)d_in[15];
    p.ws  = (float*)d_ws;
    p.out = (float*)d_out;

    void* args[] = { (void*)&p };
    hipLaunchCooperativeKernel((void*)k_fused, dim3(512), dim3(256), args, 0, stream);
}

// Round 4
// 274.933 us; speedup vs baseline: 1.6452x; 1.6452x over previous
//
#include <hip/hip_runtime.h>

#define EPS 1e-5f

// Problem dims (fixed by setup_inputs)
constexpr int T  = 512;
constexpr int B  = 64;
constexpr int HU = 1024;
constexpr int S  = 1024;
constexpr int P  = T * B;        // 32768 pairs
constexpr int C  = B * HU;       // 65536 output columns
constexpr int TSPLIT = 16;       // tau-split for k_wsum

// ws layout (in floats)
constexpr size_t OFF_SIW0   = 0;          // [64][10]
constexpr size_t OFF_SCORES = 1024;       // [32768]
constexpr size_t OFF_A      = 34816;      // [512]
constexpr size_t OFF_PART   = 35840;      // [16][65536]

// ---------------------------------------------------------------------------
// K0: siW0[b][j] = si[b,:] . W0[0:1024, j]   (64 x 10)
// ---------------------------------------------------------------------------
__global__ __launch_bounds__(256) void k_siw0(const float* __restrict__ si,
                                              const float* __restrict__ W0,
                                              float* __restrict__ out) {
    const int b   = blockIdx.x;     // 0..63
    const int tid = threadIdx.x;    // covers k = 4*tid .. 4*tid+3
    const float4 sv = ((const float4*)(si + (size_t)b * S))[tid];
    const float* wp = W0 + (size_t)(4 * tid) * 10;

    float acc[10];
#pragma unroll
    for (int j = 0; j < 10; ++j) acc[j] = 0.f;
#pragma unroll
    for (int d = 0; d < 4; ++d) {
        const float hx = (&sv.x)[d];
#pragma unroll
        for (int j = 0; j < 10; ++j) acc[j] = fmaf(hx, wp[d * 10 + j], acc[j]);
    }
#pragma unroll
    for (int j = 0; j < 10; ++j) {
#pragma unroll
        for (int off = 32; off > 0; off >>= 1)
            acc[j] += __shfl_down(acc[j], off, 64);
    }
    __shared__ float red[4][10];
    const int wv = tid >> 6, ln = tid & 63;
    if (ln == 0) {
#pragma unroll
        for (int j = 0; j < 10; ++j) red[wv][j] = acc[j];
    }
    __syncthreads();
    if (tid < 10)
        out[(size_t)b * 10 + tid] =
            red[0][tid] + red[1][tid] + red[2][tid] + red[3][tid];
}

// ---------------------------------------------------------------------------
// K1: per-pair MLP scores via LDS staging.
// Block = t. The old direct-load pattern had 4KB lane stride -> addr bits
// [8:11] (channel select) came only from k -> all 64 lanes camped on ONE
// L2/DRAM channel (measured 590 GB/s). Fix: stage h[t] into LDS in 64KB
// chunks with 1KB-contiguous wave loads (channels spread), then lane-owns-row
// ds_read_b128 with XOR-swizzled slots (<=2-way bank alias = free).
// ---------------------------------------------------------------------------
__global__ __launch_bounds__(256) void k_scores(
    const float* __restrict__ h,  const float* __restrict__ W0,
    const float* __restrict__ siW0,
    const float* __restrict__ b0, const float* __restrict__ g0,
    const float* __restrict__ be0,const float* __restrict__ m0,
    const float* __restrict__ v0,
    const float* __restrict__ W1, const float* __restrict__ b1,
    const float* __restrict__ g1, const float* __restrict__ be1,
    const float* __restrict__ m1, const float* __restrict__ v1,
    const float* __restrict__ W2, const float* __restrict__ b2,
    float* __restrict__ scores) {
    const int t   = blockIdx.x;
    const int tid = threadIdx.x;
    const int wv  = tid >> 6;            // 0..3
    const int ln  = tid & 63;            // row b for compute phase
    const float* hblk = h + (size_t)t * 64 * HU;

    __shared__ float lds[64 * 256];      // 64KB staging chunk (xor-swizzled)
    __shared__ float s_part[4][64][10];

    float acc[10];
#pragma unroll
    for (int j = 0; j < 10; ++j) acc[j] = 0.f;

    for (int cc = 0; cc < 4; ++cc) {     // k-chunks of 256 floats
        if (cc) __syncthreads();         // prior compute done before overwrite
        // ---- stage: 16 iters x 256 threads; wave load = 1KB contiguous ----
        const float* hc = hblk + cc * 256;
#pragma unroll
        for (int it = 0; it < 16; ++it) {
            const int f = it * 256 + tid;
            const int r = f >> 6;        // 0..63 (row)
            const int q = f & 63;        // float4 slot within row chunk
            const float4 v = *(const float4*)(hc + (size_t)r * HU + q * 4);
            *(float4*)(&lds[r * 256 + ((q ^ r) << 2)]) = v;
        }
        __syncthreads();
        // ---- compute: wave wv covers slots [16wv,16wv+16); lane = row ln ---
        const int qbase = __builtin_amdgcn_readfirstlane(wv * 16);
#pragma unroll
        for (int qi = 0; qi < 16; ++qi) {
            const int qq = qbase + qi;                       // wave-uniform
            const float4 hv =
                *(const float4*)(&lds[ln * 256 + ((qq ^ ln) << 2)]);
            const float* wp = W0 + (size_t)(1024 + cc * 256 + qq * 4) * 10;
#pragma unroll
            for (int d = 0; d < 4; ++d) {
                const float hx = (&hv.x)[d];
#pragma unroll
                for (int j = 0; j < 10; ++j)
                    acc[j] = fmaf(hx, wp[d * 10 + j], acc[j]);
            }
        }
    }

#pragma unroll
    for (int j = 0; j < 10; ++j) s_part[wv][ln][j] = acc[j];
    __syncthreads();

    if (wv == 0) {
        float y[10];
#pragma unroll
        for (int j = 0; j < 10; ++j) {
            float u = s_part[0][ln][j] + s_part[1][ln][j] + s_part[2][ln][j] +
                      s_part[3][ln][j] + siW0[(size_t)ln * 10 + j] + b0[j];
            u = (u - m0[j]) * (1.0f / sqrtf(v0[j] + EPS)) * g0[j] + be0[j];
            y[j] = fmaxf(u, 0.f);
        }
        float z[5];
#pragma unroll
        for (int i = 0; i < 5; ++i) {
            float u = b1[i];
#pragma unroll
            for (int j = 0; j < 10; ++j) u = fmaf(y[j], W1[j * 5 + i], u);
            u = (u - m1[i]) * (1.0f / sqrtf(v1[i] + EPS)) * g1[i] + be1[i];
            z[i] = fmaxf(u, 0.f);
        }
        float sc = b2[0];
#pragma unroll
        for (int i = 0; i < 5; ++i) sc = fmaf(z[i], W2[i], sc);
        scores[t * 64 + ln] = sc;
    }
}

// ---------------------------------------------------------------------------
// K2: global softmax over all 32768 scores; write a[0:512] (flat order).
// ---------------------------------------------------------------------------
__global__ __launch_bounds__(1024) void k_softmax(const float* __restrict__ scores,
                                                  float* __restrict__ a) {
    const int tid = threadIdx.x;   // 1024 threads
    __shared__ float red[16];
    __shared__ float s_m, s_z;

    float v[32];
#pragma unroll
    for (int i = 0; i < 32; ++i) v[i] = scores[tid + i * 1024];

    float mx = v[0];
#pragma unroll
    for (int i = 1; i < 32; ++i) mx = fmaxf(mx, v[i]);
#pragma unroll
    for (int off = 32; off > 0; off >>= 1)
        mx = fmaxf(mx, __shfl_down(mx, off, 64));
    if ((tid & 63) == 0) red[tid >> 6] = mx;
    __syncthreads();
    if (tid == 0) {
        float m = red[0];
        for (int i = 1; i < 16; ++i) m = fmaxf(m, red[i]);
        s_m = m;
    }
    __syncthreads();
    const float m = s_m;

    float sum = 0.f;
#pragma unroll
    for (int i = 0; i < 32; ++i) sum += __expf(v[i] - m);
#pragma unroll
    for (int off = 32; off > 0; off >>= 1)
        sum += __shfl_down(sum, off, 64);
    if ((tid & 63) == 0) red[tid >> 6] = sum;
    __syncthreads();
    if (tid == 0) {
        float z = 0.f;
        for (int i = 0; i < 16; ++i) z += red[i];
        s_z = z;
    }
    __syncthreads();

    if (tid < T) a[tid] = expf(scores[tid] - m) / s_z;
}

// ---------------------------------------------------------------------------
// K3: partial weighted sums. block = (ts, cb); ts in [0,16) covers 32 taus,
// cb in [0,64) covers 1024 columns. Coalesced float4 column reads.
// ---------------------------------------------------------------------------
__global__ __launch_bounds__(256) void k_wsum(const float* __restrict__ h,
                                              const float* __restrict__ a,
                                              float* __restrict__ part) {
    const int cb = blockIdx.x & 63;
    const int ts = blockIdx.x >> 6;      // 0..15
    const int c  = cb * 1024 + threadIdx.x * 4;
    const float* hp = h + (size_t)ts * 32 * C + c;
    const float* ap = a + ts * 32;

    float4 acc = {0.f, 0.f, 0.f, 0.f};
#pragma unroll 4
    for (int i = 0; i < 32; ++i) {
        const float av = ap[i];                       // uniform -> s_load
        const float4 hv = *(const float4*)(hp + (size_t)i * C);
        acc.x = fmaf(av, hv.x, acc.x);
        acc.y = fmaf(av, hv.y, acc.y);
        acc.z = fmaf(av, hv.z, acc.z);
        acc.w = fmaf(av, hv.w, acc.w);
    }
    *(float4*)(part + (size_t)ts * C + c) = acc;
}

// ---------------------------------------------------------------------------
// K4: reduce 16 partials -> out (64 x 1024)
// ---------------------------------------------------------------------------
__global__ __launch_bounds__(256) void k_reduce(const float* __restrict__ part,
                                                float* __restrict__ out) {
    const int c = blockIdx.x * 1024 + threadIdx.x * 4;
    float4 s = {0.f, 0.f, 0.f, 0.f};
#pragma unroll
    for (int ts = 0; ts < TSPLIT; ++ts) {
        const float4 v = *(const float4*)(part + (size_t)ts * C + c);
        s.x += v.x; s.y += v.y; s.z += v.z; s.w += v.w;
    }
    *(float4*)(out + c) = s;
}

// ---------------------------------------------------------------------------
extern "C" void kernel_launch(void* const* d_in, const int* in_sizes, int n_in,
                              void* d_out, int out_size, void* d_ws, size_t ws_size,
                              hipStream_t stream) {
    const float* si  = (const float*)d_in[0];
    const float* h   = (const float*)d_in[1];
    const float* W0  = (const float*)d_in[2];
    const float* b0  = (const float*)d_in[3];
    const float* g0  = (const float*)d_in[4];
    const float* be0 = (const float*)d_in[5];
    const float* m0  = (const float*)d_in[6];
    const float* v0  = (const float*)d_in[7];
    const float* W1  = (const float*)d_in[8];
    const float* b1  = (const float*)d_in[9];
    const float* g1  = (const float*)d_in[10];
    const float* be1 = (const float*)d_in[11];
    const float* m1  = (const float*)d_in[12];
    const float* v1  = (const float*)d_in[13];
    const float* W2  = (const float*)d_in[14];
    const float* b2  = (const float*)d_in[15];

    float* ws     = (float*)d_ws;
    float* siW0   = ws + OFF_SIW0;
    float* scores = ws + OFF_SCORES;
    float* a      = ws + OFF_A;
    float* part   = ws + OFF_PART;
    float* out    = (float*)d_out;

    hipLaunchKernelGGL(k_siw0,    dim3(64),   dim3(256),  0, stream, si, W0, siW0);
    hipLaunchKernelGGL(k_scores,  dim3(512),  dim3(256),  0, stream, h, W0, siW0,
                       b0, g0, be0, m0, v0, W1, b1, g1, be1, m1, v1, W2, b2, scores);
    hipLaunchKernelGGL(k_softmax, dim3(1),    dim3(1024), 0, stream, scores, a);
    hipLaunchKernelGGL(k_wsum,    dim3(1024), dim3(256),  0, stream, h, a, part);
    hipLaunchKernelGGL(k_reduce,  dim3(64),   dim3(256),  0, stream, part, out);
}